// Round 1
// baseline (137.743 us; speedup 1.0000x reference)
//
#include <hip/hip_runtime.h>
#include <hip/hip_bf16.h>

// BilinearPooling: out[i,k] = mean_j(conv1[i,j]) * conv2[i,k]
// B=256, J=K=14*14*256=50176. Pure memory-bound: 154 MB total traffic.
//
// One block per row (grid=256 == CU count), 1024 threads (16 waves/CU).
// Phase 1: float4 row reduction of conv1 -> mean.
// Phase 2: float4 streaming scale of conv2 -> out.

#define ROW_ELEMS 50176          // 14*14*256
#define ROW_VEC   (ROW_ELEMS/4)  // 12544 float4 per row
#define BLOCK_THREADS 1024

__global__ __launch_bounds__(BLOCK_THREADS)
void BilinearPooling_36490042147537_kernel(const float4* __restrict__ c1,
                                           const float4* __restrict__ c2,
                                           float4* __restrict__ out) {
    const int row = blockIdx.x;
    const int tid = threadIdx.x;

    const float4* __restrict__ r1 = c1 + (size_t)row * ROW_VEC;

    // ---- Phase 1: reduce conv1 row ----
    float s = 0.0f;
    for (int idx = tid; idx < ROW_VEC; idx += BLOCK_THREADS) {
        float4 v = r1[idx];
        s += (v.x + v.y) + (v.z + v.w);
    }

    // wave-64 shuffle reduction
    #pragma unroll
    for (int off = 32; off > 0; off >>= 1)
        s += __shfl_down(s, off, 64);

    __shared__ float wsum[BLOCK_THREADS / 64];
    __shared__ float mean_s;
    const int lane = tid & 63;
    const int wid  = tid >> 6;
    if (lane == 0) wsum[wid] = s;
    __syncthreads();
    if (tid == 0) {
        float t = 0.0f;
        #pragma unroll
        for (int i = 0; i < BLOCK_THREADS / 64; ++i) t += wsum[i];
        mean_s = t * (1.0f / (float)ROW_ELEMS);
    }
    __syncthreads();
    const float m = mean_s;

    // ---- Phase 2: scale conv2 row ----
    const float4* __restrict__ r2 = c2 + (size_t)row * ROW_VEC;
    float4* __restrict__ ro = out + (size_t)row * ROW_VEC;
    for (int idx = tid; idx < ROW_VEC; idx += BLOCK_THREADS) {
        float4 v = r2[idx];
        v.x *= m; v.y *= m; v.z *= m; v.w *= m;
        ro[idx] = v;
    }
}

extern "C" void kernel_launch(void* const* d_in, const int* in_sizes, int n_in,
                              void* d_out, int out_size, void* d_ws, size_t ws_size,
                              hipStream_t stream) {
    const float4* c1 = (const float4*)d_in[0];
    const float4* c2 = (const float4*)d_in[1];
    float4* out = (float4*)d_out;

    const int B = 256;  // rows; out_size == 256*50176
    BilinearPooling_36490042147537_kernel<<<B, BLOCK_THREADS, 0, stream>>>(c1, c2, out);
}